// Round 1
// baseline (79.291 us; speedup 1.0000x reference)
//
#include <hip/hip_runtime.h>
#include <math.h>
#include <limits.h>

// Problem constants (fixed by reference setup_inputs)
constexpr int N = 8;
constexpr int H = 256;
constexpr int W = 256;
constexpr int NPIX = N * H * W;            // 524288
constexpr float FEPS = 1e-6f;
constexpr int   RSENT = 20000;             // row-empty sentinel: RSENT^2=4e8 >> legit max 130050
constexpr int   EMPTY_THRESH = 300000000;  // > legit max 130050, < RSENT^2
constexpr int   NROW = N * H;              // 2048 per-row partial slots (layout == old kernel)
constexpr int   NBLK = NROW / 2;           // 1024 fused blocks, 2 output rows each
constexpr int   BIGC = 1 << 20;
constexpr unsigned long long MAGIC = 0x9E3779B97F4A7C15ull; // halves differ -> no uniform
                                                            // poison pattern can match

// ws layout:
//   float parts[5][NROW]  : q=0: p*t, 1: p, 2: t, 3: phi*p, 4: focal   (40 KB)
//   u64   flags[NBLK]     : per-block completion magic                  (8 KB)

// ---- wave-wide exact 1D row distance scan: lane handles px = 4*lane .. 4*lane+3 ----
// rf[k] = min over fg qx of |px-qx| (RSENT if none, clamped >255), rb[k] same for bg.
__device__ __forceinline__ void wave_scan_row(const float4 tv, const int lane,
                                              int rf[4], int rb[4])
{
    const int px0 = lane << 2;
    const float tvv[4] = {tv.x, tv.y, tv.z, tv.w};
    int af[4], ab[4], bf[4], bb[4];
    #pragma unroll
    for (int k = 0; k < 4; ++k) {
        const bool fg = tvv[k] > 0.5f;
        const int cf = fg ? 0 : BIGC;
        const int cb = fg ? BIGC : 0;
        af[k] = cf - (px0 + k);   // forward:  fwd[i] = i + min_{j<=i}(c_j - j)
        ab[k] = cb - (px0 + k);
        bf[k] = cf + (px0 + k);   // backward: bwd[i] = -i + min_{j>=i}(c_j + j)
        bb[k] = cb + (px0 + k);
    }
    // local prefix mins (forward) / suffix mins (backward)
    int pf[4], pb[4], qf[4], qb[4];
    pf[0] = af[0]; pb[0] = ab[0];
    #pragma unroll
    for (int k = 1; k < 4; ++k) { pf[k] = min(pf[k-1], af[k]); pb[k] = min(pb[k-1], ab[k]); }
    qf[3] = bf[3]; qb[3] = bb[3];
    #pragma unroll
    for (int k = 2; k >= 0; --k) { qf[k] = min(qf[k+1], bf[k]); qb[k] = min(qb[k+1], bb[k]); }

    // wave-level inclusive min-scans of the lane aggregates (both directions, fg+bg)
    int sf = pf[3], sb = pb[3], tf = qf[0], tb = qb[0];
    #pragma unroll
    for (int off = 1; off < 64; off <<= 1) {
        const int uf = __shfl_up(sf, off, 64);
        const int ub = __shfl_up(sb, off, 64);
        const int df = __shfl_down(tf, off, 64);
        const int db = __shfl_down(tb, off, 64);
        if (lane >= off)      { sf = min(sf, uf); sb = min(sb, ub); }
        if (lane + off < 64)  { tf = min(tf, df); tb = min(tb, db); }
    }
    // exclusive versions
    int ef = __shfl_up(sf, 1, 64);   if (lane == 0)  ef = INT_MAX / 2;
    int eb = __shfl_up(sb, 1, 64);   if (lane == 0)  eb = INT_MAX / 2;
    int xf = __shfl_down(tf, 1, 64); if (lane == 63) xf = INT_MAX / 2;
    int xb = __shfl_down(tb, 1, 64); if (lane == 63) xb = INT_MAX / 2;

    #pragma unroll
    for (int k = 0; k < 4; ++k) {
        const int p = px0 + k;
        int F  = p + min(ef, pf[k]);
        int Bv = min(xf, qf[k]) - p;
        int r  = min(F, Bv); if (r > 255) r = RSENT;
        rf[k] = r;
        F  = p + min(eb, pb[k]);
        Bv = min(xb, qb[k]) - p;
        r  = min(F, Bv); if (r > 255) r = RSENT;
        rb[k] = r;
    }
}

__global__ __launch_bounds__(256, 4) void fused_kernel(
    const float* __restrict__ pred, const float* __restrict__ tgt,
    float* __restrict__ parts, unsigned long long* __restrict__ flags,
    float* __restrict__ out)
{
    const int blk  = blockIdx.x;            // n*128 + (py>>1)
    const int n    = blk >> 7;
    const int py0  = (blk & 127) << 1;
    const int py1  = py0 + 1;
    const int px   = threadIdx.x;
    const int lane = px & 63;
    const int wid  = px >> 6;

    __shared__ unsigned int rows[8][W];     // packed rf | rb<<16, slot s <-> qy = py0-3+s
    __shared__ float smem[2][20];
    __shared__ float smf[8];
    __shared__ float sratio[8];

    const float* __restrict__ timg = tgt  + (size_t)n * (H * W);
    const float* __restrict__ pimg = pred + (size_t)n * (H * W);

    // ---- window row-scans: wave w computes slots w and w+4 entirely in-wave ----
    {
        const int s1 = wid, s2 = wid + 4;
        const int qy1 = py0 - 3 + s1;
        const int qy2 = py0 - 3 + s2;
        const bool va = (qy1 >= 0) & (qy1 < H);   // wave-uniform
        const bool vb = (qy2 >= 0) & (qy2 < H);
        float4 tva, tvb;
        if (va) tva = *(const float4*)(timg + qy1 * W + (lane << 2));
        if (vb) tvb = *(const float4*)(timg + qy2 * W + (lane << 2));
        if (va) {
            int rf[4], rb[4];
            wave_scan_row(tva, lane, rf, rb);
            uint4 pk;
            pk.x = (unsigned)rf[0] | ((unsigned)rb[0] << 16);
            pk.y = (unsigned)rf[1] | ((unsigned)rb[1] << 16);
            pk.z = (unsigned)rf[2] | ((unsigned)rb[2] << 16);
            pk.w = (unsigned)rf[3] | ((unsigned)rb[3] << 16);
            *(uint4*)&rows[s1][lane << 2] = pk;
        }
        if (vb) {
            int rf[4], rb[4];
            wave_scan_row(tvb, lane, rf, rb);
            uint4 pk;
            pk.x = (unsigned)rf[0] | ((unsigned)rb[0] << 16);
            pk.y = (unsigned)rf[1] | ((unsigned)rb[1] << 16);
            pk.z = (unsigned)rf[2] | ((unsigned)rb[2] << 16);
            pk.w = (unsigned)rf[3] | ((unsigned)rb[3] << 16);
            *(uint4*)&rows[s2][lane << 2] = pk;
        }
    }

    // hot loads for the loss phase (issue early, overlap with barrier + window min)
    const float x0 = pimg[py0 * W + px];
    const float x1 = pimg[py1 * W + px];
    const float t0 = timg[py0 * W + px];
    const float t1 = timg[py1 * W + px];

    __syncthreads();

    // ---- windowed column pass for both output rows from LDS ----
    int bf0 = INT_MAX, bb0 = INT_MAX, bf1 = INT_MAX, bb1 = INT_MAX;
    #pragma unroll
    for (int s = 0; s < 8; ++s) {
        const int qy = py0 - 3 + s;
        if (qy >= 0 && qy < H) {            // wave-uniform
            const unsigned v = rows[s][px];
            const int rfv = (int)(v & 0xffffu);
            const int rbv = (int)(v >> 16);
            const int rf2 = rfv * rfv, rb2 = rbv * rbv;
            const int d0 = s - 3, d1 = s - 4;
            bf0 = min(bf0, rf2 + d0 * d0); bb0 = min(bb0, rb2 + d0 * d0);
            bf1 = min(bf1, rf2 + d1 * d1); bb1 = min(bb1, rb2 + d1 * d1);
        }
    }

    // ---- rare exact fallback: extend outward, recomputing rows on demand ----
    // upward: qy = py0-4, py0-5, ...  (dist to row0 = du0, row1 = du0+1)
    for (int qy = py0 - 4; qy >= 0; --qy) {
        const int du0 = py0 - qy, du1 = du0 + 1;
        const int d0s = du0 * du0, d1s = du1 * du1;
        if (!__any((d0s < bf0) | (d0s < bb0) | (d1s < bf1) | (d1s < bb1))) break;
        const float4 tv = *(const float4*)(timg + qy * W + (lane << 2));
        int rf[4], rb[4];
        wave_scan_row(tv, lane, rf, rb);
        const int o = px >> 2;              // owner lane of this thread's px
        const int k = px & 3;
        int f0 = __shfl(rf[0], o, 64), f1 = __shfl(rf[1], o, 64);
        int f2 = __shfl(rf[2], o, 64), f3 = __shfl(rf[3], o, 64);
        int g0 = __shfl(rb[0], o, 64), g1 = __shfl(rb[1], o, 64);
        int g2 = __shfl(rb[2], o, 64), g3 = __shfl(rb[3], o, 64);
        const int irf = (k == 0) ? f0 : (k == 1) ? f1 : (k == 2) ? f2 : f3;
        const int irb = (k == 0) ? g0 : (k == 1) ? g1 : (k == 2) ? g2 : g3;
        const int rf2 = irf * irf, rb2 = irb * irb;
        bf0 = min(bf0, rf2 + d0s); bb0 = min(bb0, rb2 + d0s);
        bf1 = min(bf1, rf2 + d1s); bb1 = min(bb1, rb2 + d1s);
    }
    // downward: qy = py0+5, py0+6, ...  (dist to row0 = dd0, row1 = dd0-1)
    for (int qy = py0 + 5; qy < H; ++qy) {
        const int dd0 = qy - py0, dd1 = dd0 - 1;
        const int d0s = dd0 * dd0, d1s = dd1 * dd1;
        if (!__any((d0s < bf0) | (d0s < bb0) | (d1s < bf1) | (d1s < bb1))) break;
        const float4 tv = *(const float4*)(timg + qy * W + (lane << 2));
        int rf[4], rb[4];
        wave_scan_row(tv, lane, rf, rb);
        const int o = px >> 2;
        const int k = px & 3;
        int f0 = __shfl(rf[0], o, 64), f1 = __shfl(rf[1], o, 64);
        int f2 = __shfl(rf[2], o, 64), f3 = __shfl(rf[3], o, 64);
        int g0 = __shfl(rb[0], o, 64), g1 = __shfl(rb[1], o, 64);
        int g2 = __shfl(rb[2], o, 64), g3 = __shfl(rb[3], o, 64);
        const int irf = (k == 0) ? f0 : (k == 1) ? f1 : (k == 2) ? f2 : f3;
        const int irb = (k == 0) ? g0 : (k == 1) ? g1 : (k == 2) ? g2 : g3;
        const int rf2 = irf * irf, rb2 = irb * irb;
        bf0 = min(bf0, rf2 + d0s); bb0 = min(bb0, rb2 + d0s);
        bf1 = min(bf1, rf2 + d1s); bb1 = min(bb1, rb2 + d1s);
    }

    // ---- loss math (identical ops/order to the verified kernel) ----
    const float MAXD2 = (float)((H - 1) * (H - 1) + (W - 1) * (W - 1));
    const float Df0 = (bf0 > EMPTY_THRESH) ? MAXD2 : (float)bf0;
    const float Db0 = (bb0 > EMPTY_THRESH) ? MAXD2 : (float)bb0;
    const float Df1 = (bf1 > EMPTY_THRESH) ? MAXD2 : (float)bf1;
    const float Db1 = (bb1 > EMPTY_THRESH) ? MAXD2 : (float)bb1;

    const float p0   = 1.0f / (1.0f + expf(-x0));
    const float phi0 = (t0 > 0.5f) ? -sqrtf(Db0) : sqrtf(Df0);
    const float pc0  = fminf(fmaxf(p0, FEPS), 1.0f - FEPS);
    const float pt0  = pc0 * t0 + (1.0f - pc0) * (1.0f - t0);
    const float at0  = 0.25f * t0 + 0.75f * (1.0f - t0);
    const float om0  = 1.0f - pt0;
    const float fo0  = -at0 * om0 * om0 * logf(pt0);

    const float p1   = 1.0f / (1.0f + expf(-x1));
    const float phi1 = (t1 > 0.5f) ? -sqrtf(Db1) : sqrtf(Df1);
    const float pc1  = fminf(fmaxf(p1, FEPS), 1.0f - FEPS);
    const float pt1  = pc1 * t1 + (1.0f - pc1) * (1.0f - t1);
    const float at1  = 0.25f * t1 + 0.75f * (1.0f - t1);
    const float om1  = 1.0f - pt1;
    const float fo1  = -at1 * om1 * om1 * logf(pt1);

    // ---- per-row block reductions (same tree as before -> bitwise-identical parts) ----
    float v50[5] = { p0 * t0, p0, t0, phi0 * p0, fo0 };
    float v51[5] = { p1 * t1, p1, t1, phi1 * p1, fo1 };
    #pragma unroll
    for (int q = 0; q < 5; ++q) {
        float a = v50[q], b = v51[q];
        #pragma unroll
        for (int off = 32; off > 0; off >>= 1) {
            a += __shfl_down(a, off, 64);
            b += __shfl_down(b, off, 64);
        }
        v50[q] = a; v51[q] = b;
    }
    if (lane == 0) {
        #pragma unroll
        for (int q = 0; q < 5; ++q) {
            smem[0][wid * 5 + q] = v50[q];
            smem[1][wid * 5 + q] = v51[q];
        }
    }
    __syncthreads();
    if (px == 0) {
        #pragma unroll
        for (int r = 0; r < 2; ++r) {
            #pragma unroll
            for (int q = 0; q < 5; ++q) {
                const float v = smem[r][q] + smem[r][5 + q] + smem[r][10 + q] + smem[r][15 + q];
                __hip_atomic_store(&parts[q * NROW + blk * 2 + r], v,
                                   __ATOMIC_RELAXED, __HIP_MEMORY_SCOPE_AGENT);
            }
        }
        __hip_atomic_store(&flags[blk], MAGIC, __ATOMIC_RELEASE, __HIP_MEMORY_SCOPE_AGENT);
    }

    // ---- block 0: wait for all producers, then finalize (identical reduction) ----
    if (blk == 0) {
        const int tid = px;
        bool done = false;
        int guard = 0;
        do {
            bool mine = true;
            #pragma unroll
            for (int k = 0; k < NBLK / 256; ++k) {
                const unsigned long long v = __hip_atomic_load(
                    &flags[tid + k * 256], __ATOMIC_ACQUIRE, __HIP_MEMORY_SCOPE_AGENT);
                mine = mine && (v == MAGIC);
            }
            done = (__syncthreads_and((int)mine) != 0);
        } while (!done && (++guard < (1 << 26)));

        // boundary + focal: global sums over all NROW partials
        float bp = 0.0f, fc = 0.0f;
        for (int k = tid; k < NROW; k += 256) {
            bp += __hip_atomic_load(&parts[3 * NROW + k], __ATOMIC_RELAXED, __HIP_MEMORY_SCOPE_AGENT);
            fc += __hip_atomic_load(&parts[4 * NROW + k], __ATOMIC_RELAXED, __HIP_MEMORY_SCOPE_AGENT);
        }
        #pragma unroll
        for (int off = 32; off > 0; off >>= 1) {
            bp += __shfl_down(bp, off, 64);
            fc += __shfl_down(fc, off, 64);
        }
        if (lane == 0) { smf[wid * 2] = bp; smf[wid * 2 + 1] = fc; }

        // dice: each wave handles 2 images (256 partials each)
        #pragma unroll
        for (int mi = 0; mi < 2; ++mi) {
            const int m = wid * 2 + mi;
            float A = 0.f, S = 0.f, C = 0.f;
            #pragma unroll
            for (int k = 0; k < 4; ++k) {
                const int i = m * 256 + k * 64 + lane;
                A += __hip_atomic_load(&parts[0 * NROW + i], __ATOMIC_RELAXED, __HIP_MEMORY_SCOPE_AGENT);
                S += __hip_atomic_load(&parts[1 * NROW + i], __ATOMIC_RELAXED, __HIP_MEMORY_SCOPE_AGENT);
                C += __hip_atomic_load(&parts[2 * NROW + i], __ATOMIC_RELAXED, __HIP_MEMORY_SCOPE_AGENT);
            }
            #pragma unroll
            for (int off = 32; off > 0; off >>= 1) {
                A += __shfl_down(A, off, 64);
                S += __shfl_down(S, off, 64);
                C += __shfl_down(C, off, 64);
            }
            if (lane == 0) sratio[m] = (2.0f * A + FEPS) / (S + C + FEPS);
        }
        __syncthreads();
        if (tid == 0) {
            const float B = smf[0] + smf[2] + smf[4] + smf[6];
            const float F = smf[1] + smf[3] + smf[5] + smf[7];
            float dacc = 0.0f;
            #pragma unroll
            for (int m = 0; m < 8; ++m) dacc += sratio[m];
            const float dice_val     = 1.0f - dacc / (float)N;
            const float boundary_val = B / (float)NPIX;
            const float focal_val    = F / (float)NPIX;
            out[0] = dice_val + boundary_val + focal_val;   // loss
            out[1] = dice_val;
            out[2] = boundary_val;
            out[3] = focal_val;
        }
    }
}

extern "C" void kernel_launch(void* const* d_in, const int* in_sizes, int n_in,
                              void* d_out, int out_size, void* d_ws, size_t ws_size,
                              hipStream_t stream)
{
    const float* pred = (const float*)d_in[0];
    const float* tgt  = (const float*)d_in[1];
    float* out = (float*)d_out;

    float* parts = (float*)d_ws;                                        // 40 KB
    unsigned long long* flags =
        (unsigned long long*)((char*)d_ws + (size_t)5 * NROW * sizeof(float)); // 8 KB

    fused_kernel<<<NBLK, 256, 0, stream>>>(pred, tgt, parts, flags, out);
}

// Round 2
// 70.159 us; speedup vs baseline: 1.1302x; 1.1302x over previous
//
#include <hip/hip_runtime.h>
#include <math.h>
#include <limits.h>

// Problem constants (fixed by reference setup_inputs)
constexpr int N = 8;
constexpr int H = 256;
constexpr int W = 256;
constexpr int NPIX = N * H * W;            // 524288
constexpr float FEPS = 1e-6f;
constexpr int   RSENT = 20000;             // row-empty sentinel: RSENT^2=4e8 >> legit max 130050
constexpr int   EMPTY_THRESH = 300000000;  // > legit max 130050, < RSENT^2
constexpr int   NROW = N * H;              // 2048 per-row partial slots (layout == old kernel)
constexpr int   NBLK = NROW / 2;           // 1024 fused blocks, 2 output rows each
constexpr int   BIGC = 1 << 20;
constexpr unsigned long long MAGIC = 0x9E3779B97F4A7C15ull; // halves differ -> no uniform
                                                            // poison pattern can match

// ws layout:
//   float parts[5][NROW]  : q=0: p*t, 1: p, 2: t, 3: phi*p, 4: focal   (40 KB)
//   u64   flags[NBLK]     : per-block completion magic                  (8 KB)

// ---- wave-wide exact 1D row distance scan: lane handles px = 4*lane .. 4*lane+3 ----
// rf[k] = min over fg qx of |px-qx| (RSENT if none, clamped >255), rb[k] same for bg.
__device__ __forceinline__ void wave_scan_row(const float4 tv, const int lane,
                                              int rf[4], int rb[4])
{
    const int px0 = lane << 2;
    const float tvv[4] = {tv.x, tv.y, tv.z, tv.w};
    int af[4], ab[4], bf[4], bb[4];
    #pragma unroll
    for (int k = 0; k < 4; ++k) {
        const bool fg = tvv[k] > 0.5f;
        const int cf = fg ? 0 : BIGC;
        const int cb = fg ? BIGC : 0;
        af[k] = cf - (px0 + k);   // forward:  fwd[i] = i + min_{j<=i}(c_j - j)
        ab[k] = cb - (px0 + k);
        bf[k] = cf + (px0 + k);   // backward: bwd[i] = -i + min_{j>=i}(c_j + j)
        bb[k] = cb + (px0 + k);
    }
    // local prefix mins (forward) / suffix mins (backward)
    int pf[4], pb[4], qf[4], qb[4];
    pf[0] = af[0]; pb[0] = ab[0];
    #pragma unroll
    for (int k = 1; k < 4; ++k) { pf[k] = min(pf[k-1], af[k]); pb[k] = min(pb[k-1], ab[k]); }
    qf[3] = bf[3]; qb[3] = bb[3];
    #pragma unroll
    for (int k = 2; k >= 0; --k) { qf[k] = min(qf[k+1], bf[k]); qb[k] = min(qb[k+1], bb[k]); }

    // wave-level inclusive min-scans of the lane aggregates (both directions, fg+bg)
    int sf = pf[3], sb = pb[3], tf = qf[0], tb = qb[0];
    #pragma unroll
    for (int off = 1; off < 64; off <<= 1) {
        const int uf = __shfl_up(sf, off, 64);
        const int ub = __shfl_up(sb, off, 64);
        const int df = __shfl_down(tf, off, 64);
        const int db = __shfl_down(tb, off, 64);
        if (lane >= off)      { sf = min(sf, uf); sb = min(sb, ub); }
        if (lane + off < 64)  { tf = min(tf, df); tb = min(tb, db); }
    }
    // exclusive versions
    int ef = __shfl_up(sf, 1, 64);   if (lane == 0)  ef = INT_MAX / 2;
    int eb = __shfl_up(sb, 1, 64);   if (lane == 0)  eb = INT_MAX / 2;
    int xf = __shfl_down(tf, 1, 64); if (lane == 63) xf = INT_MAX / 2;
    int xb = __shfl_down(tb, 1, 64); if (lane == 63) xb = INT_MAX / 2;

    #pragma unroll
    for (int k = 0; k < 4; ++k) {
        const int p = px0 + k;
        int F  = p + min(ef, pf[k]);
        int Bv = min(xf, qf[k]) - p;
        int r  = min(F, Bv); if (r > 255) r = RSENT;
        rf[k] = r;
        F  = p + min(eb, pb[k]);
        Bv = min(xb, qb[k]) - p;
        r  = min(F, Bv); if (r > 255) r = RSENT;
        rb[k] = r;
    }
}

__global__ __launch_bounds__(256, 2) void fused_kernel(
    const float* __restrict__ pred, const float* __restrict__ tgt,
    float* __restrict__ parts, unsigned long long* __restrict__ flags,
    float* __restrict__ out)
{
    const int blk  = blockIdx.x;            // n*128 + (py>>1)
    const int n    = blk >> 7;
    const int py0  = (blk & 127) << 1;
    const int py1  = py0 + 1;
    const int px   = threadIdx.x;
    const int lane = px & 63;
    const int wid  = px >> 6;

    __shared__ unsigned int rows[8][W];     // packed rf | rb<<16, slot s <-> qy = py0-3+s
    __shared__ float smem[2][20];
    __shared__ float smf[8];
    __shared__ float sratio[8];

    const float* __restrict__ timg = tgt  + (size_t)n * (H * W);
    const float* __restrict__ pimg = pred + (size_t)n * (H * W);

    // ---- window row-scans: wave w computes slots w and w+4 entirely in-wave ----
    {
        const int s1 = wid, s2 = wid + 4;
        const int qy1 = py0 - 3 + s1;
        const int qy2 = py0 - 3 + s2;
        const bool va = (qy1 >= 0) & (qy1 < H);   // wave-uniform
        const bool vb = (qy2 >= 0) & (qy2 < H);
        float4 tva, tvb;
        if (va) tva = *(const float4*)(timg + qy1 * W + (lane << 2));
        if (vb) tvb = *(const float4*)(timg + qy2 * W + (lane << 2));
        if (va) {
            int rf[4], rb[4];
            wave_scan_row(tva, lane, rf, rb);
            uint4 pk;
            pk.x = (unsigned)rf[0] | ((unsigned)rb[0] << 16);
            pk.y = (unsigned)rf[1] | ((unsigned)rb[1] << 16);
            pk.z = (unsigned)rf[2] | ((unsigned)rb[2] << 16);
            pk.w = (unsigned)rf[3] | ((unsigned)rb[3] << 16);
            *(uint4*)&rows[s1][lane << 2] = pk;
        }
        if (vb) {
            int rf[4], rb[4];
            wave_scan_row(tvb, lane, rf, rb);
            uint4 pk;
            pk.x = (unsigned)rf[0] | ((unsigned)rb[0] << 16);
            pk.y = (unsigned)rf[1] | ((unsigned)rb[1] << 16);
            pk.z = (unsigned)rf[2] | ((unsigned)rb[2] << 16);
            pk.w = (unsigned)rf[3] | ((unsigned)rb[3] << 16);
            *(uint4*)&rows[s2][lane << 2] = pk;
        }
    }

    // hot loads for the loss phase (issue early, overlap with barrier + window min)
    const float x0 = pimg[py0 * W + px];
    const float x1 = pimg[py1 * W + px];
    const float t0 = timg[py0 * W + px];
    const float t1 = timg[py1 * W + px];

    __syncthreads();

    // ---- windowed column pass for both output rows from LDS ----
    int bf0 = INT_MAX, bb0 = INT_MAX, bf1 = INT_MAX, bb1 = INT_MAX;
    #pragma unroll
    for (int s = 0; s < 8; ++s) {
        const int qy = py0 - 3 + s;
        if (qy >= 0 && qy < H) {            // wave-uniform
            const unsigned v = rows[s][px];
            const int rfv = (int)(v & 0xffffu);
            const int rbv = (int)(v >> 16);
            const int rf2 = rfv * rfv, rb2 = rbv * rbv;
            const int d0 = s - 3, d1 = s - 4;
            bf0 = min(bf0, rf2 + d0 * d0); bb0 = min(bb0, rb2 + d0 * d0);
            bf1 = min(bf1, rf2 + d1 * d1); bb1 = min(bb1, rb2 + d1 * d1);
        }
    }

    // ---- rare exact fallback: extend outward, recomputing rows on demand ----
    // upward: qy = py0-4, py0-5, ...  (dist to row0 = du0, row1 = du0+1)
    for (int qy = py0 - 4; qy >= 0; --qy) {
        const int du0 = py0 - qy, du1 = du0 + 1;
        const int d0s = du0 * du0, d1s = du1 * du1;
        if (!__any((d0s < bf0) | (d0s < bb0) | (d1s < bf1) | (d1s < bb1))) break;
        const float4 tv = *(const float4*)(timg + qy * W + (lane << 2));
        int rf[4], rb[4];
        wave_scan_row(tv, lane, rf, rb);
        const int o = px >> 2;              // owner lane of this thread's px
        const int k = px & 3;
        int f0 = __shfl(rf[0], o, 64), f1 = __shfl(rf[1], o, 64);
        int f2 = __shfl(rf[2], o, 64), f3 = __shfl(rf[3], o, 64);
        int g0 = __shfl(rb[0], o, 64), g1 = __shfl(rb[1], o, 64);
        int g2 = __shfl(rb[2], o, 64), g3 = __shfl(rb[3], o, 64);
        const int irf = (k == 0) ? f0 : (k == 1) ? f1 : (k == 2) ? f2 : f3;
        const int irb = (k == 0) ? g0 : (k == 1) ? g1 : (k == 2) ? g2 : g3;
        const int rf2 = irf * irf, rb2 = irb * irb;
        bf0 = min(bf0, rf2 + d0s); bb0 = min(bb0, rb2 + d0s);
        bf1 = min(bf1, rf2 + d1s); bb1 = min(bb1, rb2 + d1s);
    }
    // downward: qy = py0+5, py0+6, ...  (dist to row0 = dd0, row1 = dd0-1)
    for (int qy = py0 + 5; qy < H; ++qy) {
        const int dd0 = qy - py0, dd1 = dd0 - 1;
        const int d0s = dd0 * dd0, d1s = dd1 * dd1;
        if (!__any((d0s < bf0) | (d0s < bb0) | (d1s < bf1) | (d1s < bb1))) break;
        const float4 tv = *(const float4*)(timg + qy * W + (lane << 2));
        int rf[4], rb[4];
        wave_scan_row(tv, lane, rf, rb);
        const int o = px >> 2;
        const int k = px & 3;
        int f0 = __shfl(rf[0], o, 64), f1 = __shfl(rf[1], o, 64);
        int f2 = __shfl(rf[2], o, 64), f3 = __shfl(rf[3], o, 64);
        int g0 = __shfl(rb[0], o, 64), g1 = __shfl(rb[1], o, 64);
        int g2 = __shfl(rb[2], o, 64), g3 = __shfl(rb[3], o, 64);
        const int irf = (k == 0) ? f0 : (k == 1) ? f1 : (k == 2) ? f2 : f3;
        const int irb = (k == 0) ? g0 : (k == 1) ? g1 : (k == 2) ? g2 : g3;
        const int rf2 = irf * irf, rb2 = irb * irb;
        bf0 = min(bf0, rf2 + d0s); bb0 = min(bb0, rb2 + d0s);
        bf1 = min(bf1, rf2 + d1s); bb1 = min(bb1, rb2 + d1s);
    }

    // ---- loss math (identical ops/order to the verified kernel) ----
    const float MAXD2 = (float)((H - 1) * (H - 1) + (W - 1) * (W - 1));
    const float Df0 = (bf0 > EMPTY_THRESH) ? MAXD2 : (float)bf0;
    const float Db0 = (bb0 > EMPTY_THRESH) ? MAXD2 : (float)bb0;
    const float Df1 = (bf1 > EMPTY_THRESH) ? MAXD2 : (float)bf1;
    const float Db1 = (bb1 > EMPTY_THRESH) ? MAXD2 : (float)bb1;

    const float p0   = 1.0f / (1.0f + expf(-x0));
    const float phi0 = (t0 > 0.5f) ? -sqrtf(Db0) : sqrtf(Df0);
    const float pc0  = fminf(fmaxf(p0, FEPS), 1.0f - FEPS);
    const float pt0  = pc0 * t0 + (1.0f - pc0) * (1.0f - t0);
    const float at0  = 0.25f * t0 + 0.75f * (1.0f - t0);
    const float om0  = 1.0f - pt0;
    const float fo0  = -at0 * om0 * om0 * logf(pt0);

    const float p1   = 1.0f / (1.0f + expf(-x1));
    const float phi1 = (t1 > 0.5f) ? -sqrtf(Db1) : sqrtf(Df1);
    const float pc1  = fminf(fmaxf(p1, FEPS), 1.0f - FEPS);
    const float pt1  = pc1 * t1 + (1.0f - pc1) * (1.0f - t1);
    const float at1  = 0.25f * t1 + 0.75f * (1.0f - t1);
    const float om1  = 1.0f - pt1;
    const float fo1  = -at1 * om1 * om1 * logf(pt1);

    // ---- per-row block reductions (same tree as before -> bitwise-identical parts) ----
    float v50[5] = { p0 * t0, p0, t0, phi0 * p0, fo0 };
    float v51[5] = { p1 * t1, p1, t1, phi1 * p1, fo1 };
    #pragma unroll
    for (int q = 0; q < 5; ++q) {
        float a = v50[q], b = v51[q];
        #pragma unroll
        for (int off = 32; off > 0; off >>= 1) {
            a += __shfl_down(a, off, 64);
            b += __shfl_down(b, off, 64);
        }
        v50[q] = a; v51[q] = b;
    }
    if (lane == 0) {
        #pragma unroll
        for (int q = 0; q < 5; ++q) {
            smem[0][wid * 5 + q] = v50[q];
            smem[1][wid * 5 + q] = v51[q];
        }
    }
    __syncthreads();
    if (px == 0) {
        // publish parts with RELAXED agent-scope stores (write-through sc1, no wbl2),
        // then order the flag store behind them with a bare vmcnt wait.
        #pragma unroll
        for (int r = 0; r < 2; ++r) {
            #pragma unroll
            for (int q = 0; q < 5; ++q) {
                const float v = smem[r][q] + smem[r][5 + q] + smem[r][10 + q] + smem[r][15 + q];
                __hip_atomic_store(&parts[q * NROW + blk * 2 + r], v,
                                   __ATOMIC_RELAXED, __HIP_MEMORY_SCOPE_AGENT);
            }
        }
        asm volatile("s_waitcnt vmcnt(0)" ::: "memory");
        __hip_atomic_store(&flags[blk], MAGIC, __ATOMIC_RELAXED, __HIP_MEMORY_SCOPE_AGENT);
    }

    // ---- block 0: wait for all producers, then finalize (identical reduction) ----
    if (blk == 0) {
        const int tid = px;
        bool done = false;
        int guard = 0;
        do {
            bool mine = true;
            #pragma unroll
            for (int k = 0; k < NBLK / 256; ++k) {
                const unsigned long long v = __hip_atomic_load(
                    &flags[tid + k * 256], __ATOMIC_RELAXED, __HIP_MEMORY_SCOPE_AGENT);
                mine = mine && (v == MAGIC);
            }
            done = (__syncthreads_and((int)mine) != 0);
            if (!done) __builtin_amdgcn_s_sleep(2);
        } while (!done && (++guard < (1 << 26)));

        // boundary + focal: global sums over all NROW partials
        float bp = 0.0f, fc = 0.0f;
        for (int k = tid; k < NROW; k += 256) {
            bp += __hip_atomic_load(&parts[3 * NROW + k], __ATOMIC_RELAXED, __HIP_MEMORY_SCOPE_AGENT);
            fc += __hip_atomic_load(&parts[4 * NROW + k], __ATOMIC_RELAXED, __HIP_MEMORY_SCOPE_AGENT);
        }
        #pragma unroll
        for (int off = 32; off > 0; off >>= 1) {
            bp += __shfl_down(bp, off, 64);
            fc += __shfl_down(fc, off, 64);
        }
        if (lane == 0) { smf[wid * 2] = bp; smf[wid * 2 + 1] = fc; }

        // dice: each wave handles 2 images (256 partials each)
        #pragma unroll
        for (int mi = 0; mi < 2; ++mi) {
            const int m = wid * 2 + mi;
            float A = 0.f, S = 0.f, C = 0.f;
            #pragma unroll
            for (int k = 0; k < 4; ++k) {
                const int i = m * 256 + k * 64 + lane;
                A += __hip_atomic_load(&parts[0 * NROW + i], __ATOMIC_RELAXED, __HIP_MEMORY_SCOPE_AGENT);
                S += __hip_atomic_load(&parts[1 * NROW + i], __ATOMIC_RELAXED, __HIP_MEMORY_SCOPE_AGENT);
                C += __hip_atomic_load(&parts[2 * NROW + i], __ATOMIC_RELAXED, __HIP_MEMORY_SCOPE_AGENT);
            }
            #pragma unroll
            for (int off = 32; off > 0; off >>= 1) {
                A += __shfl_down(A, off, 64);
                S += __shfl_down(S, off, 64);
                C += __shfl_down(C, off, 64);
            }
            if (lane == 0) sratio[m] = (2.0f * A + FEPS) / (S + C + FEPS);
        }
        __syncthreads();
        if (tid == 0) {
            const float B = smf[0] + smf[2] + smf[4] + smf[6];
            const float F = smf[1] + smf[3] + smf[5] + smf[7];
            float dacc = 0.0f;
            #pragma unroll
            for (int m = 0; m < 8; ++m) dacc += sratio[m];
            const float dice_val     = 1.0f - dacc / (float)N;
            const float boundary_val = B / (float)NPIX;
            const float focal_val    = F / (float)NPIX;
            out[0] = dice_val + boundary_val + focal_val;   // loss
            out[1] = dice_val;
            out[2] = boundary_val;
            out[3] = focal_val;
        }
    }
}

extern "C" void kernel_launch(void* const* d_in, const int* in_sizes, int n_in,
                              void* d_out, int out_size, void* d_ws, size_t ws_size,
                              hipStream_t stream)
{
    const float* pred = (const float*)d_in[0];
    const float* tgt  = (const float*)d_in[1];
    float* out = (float*)d_out;

    float* parts = (float*)d_ws;                                        // 40 KB
    unsigned long long* flags =
        (unsigned long long*)((char*)d_ws + (size_t)5 * NROW * sizeof(float)); // 8 KB

    fused_kernel<<<NBLK, 256, 0, stream>>>(pred, tgt, parts, flags, out);
}

// Round 3
// 67.640 us; speedup vs baseline: 1.1722x; 1.0372x over previous
//
#include <hip/hip_runtime.h>
#include <math.h>
#include <limits.h>

// Problem constants (fixed by reference setup_inputs)
constexpr int N = 8;
constexpr int H = 256;
constexpr int W = 256;
constexpr int NPIX = N * H * W;            // 524288
constexpr float FEPS = 1e-6f;
constexpr int   RSENT = 20000;             // row-empty sentinel: RSENT^2=4e8 >> legit max 130050
constexpr int   EMPTY_THRESH = 300000000;  // > legit max 130050, < RSENT^2
constexpr int   NROW = N * H;              // 2048 per-row partial slots (layout == old kernel)
constexpr int   NBLK = NROW / 2;           // 1024 fused blocks, 2 output rows each
constexpr int   BIGD = 1 << 20;
constexpr unsigned long long MAGIC = 0x9E3779B97F4A7C15ull; // halves differ -> no uniform
                                                            // poison pattern can match

// ws layout:
//   float parts[5][NROW]  : q=0: p*t, 1: p, 2: t, 3: phi*p, 4: focal   (40 KB)
//   u64   flags[NBLK]     : per-block completion magic                  (8 KB)

// ---- nearest-set-bit distances from a 256-bit row mask ----
// Row pixel i <-> bit (i&63) of word (i>>6). Masks are wave-uniform (from __ballot).
// Computes r[k] = distance from pixel p = 64k+lane to nearest set bit (RSENT if none).
__device__ __forceinline__ void mask_dists(
    const unsigned long long m0, const unsigned long long m1,
    const unsigned long long m2, const unsigned long long m3,
    const int lane, int r[4])
{
    // right-chains: dJ = dist from bit0 of word J to nearest set bit in words J..3
    const int f1 = __ffsll((long long)m1), f2 = __ffsll((long long)m2), f3 = __ffsll((long long)m3);
    const int d3 = f3 ? f3 - 1 : BIGD;
    const int d2 = f2 ? f2 - 1 : 64 + d3;
    const int d1 = f1 ? f1 - 1 : 64 + d2;
    // left-chains: eJ = dist from bit63 of word J to nearest set bit in words J..0
    const int c0 = __clzll((long long)m0), c1 = __clzll((long long)m1), c2 = __clzll((long long)m2);
    const int e0 = (c0 < 64) ? c0 : BIGD;
    const int e1 = (c1 < 64) ? c1 : 64 + e0;
    const int e2 = (c2 < 64) ? c2 : 64 + e1;

    const unsigned long long mw[4] = {m0, m1, m2, m3};
    const int dnx[4] = {d1, d2, d3, BIGD};
    const int epv[4] = {BIGD, e0, e1, e2};
    #pragma unroll
    for (int k = 0; k < 4; ++k) {
        const unsigned long long x = mw[k] >> lane;          // bit0 = self
        const int fx = __ffsll((long long)x);
        const int dR = fx ? fx - 1 : (64 - lane) + dnx[k];
        const unsigned long long y = mw[k] << (63 - lane);   // bit63 = self
        const int cy = __clzll((long long)y);
        const int dL = (cy < 64) ? cy : (lane + 1) + epv[k];
        int rr = min(dL, dR);
        if (rr > 255) rr = RSENT;
        r[k] = rr;
    }
}

__global__ __launch_bounds__(256, 4) void fused_kernel(
    const float* __restrict__ pred, const float* __restrict__ tgt,
    float* __restrict__ parts, unsigned long long* __restrict__ flags,
    float* __restrict__ out)
{
    const int blk  = blockIdx.x;            // n*128 + (py>>1)
    const int n    = blk >> 7;
    const int py0  = (blk & 127) << 1;
    const int py1  = py0 + 1;
    const int px   = threadIdx.x;
    const int lane = px & 63;
    const int wid  = px >> 6;

    __shared__ unsigned int rows[8][W];     // packed rf | rb<<16, slot s <-> qy = py0-3+s
    __shared__ float smem[2][20];
    __shared__ float smf[8];
    __shared__ float sratio[8];

    const float* __restrict__ timg = tgt  + (size_t)n * (H * W);
    const float* __restrict__ pimg = pred + (size_t)n * (H * W);

    // ---- window row-scans: wave w computes slots w and w+4 entirely in-wave ----
    #pragma unroll
    for (int sh = 0; sh < 2; ++sh) {
        const int s  = wid + sh * 4;
        const int qy = py0 - 3 + s;
        if (qy >= 0 && qy < H) {            // wave-uniform
            const float a0 = timg[qy * W + lane];
            const float a1 = timg[qy * W + 64 + lane];
            const float a2 = timg[qy * W + 128 + lane];
            const float a3 = timg[qy * W + 192 + lane];
            const unsigned long long m0 = __ballot(a0 > 0.5f);
            const unsigned long long m1 = __ballot(a1 > 0.5f);
            const unsigned long long m2 = __ballot(a2 > 0.5f);
            const unsigned long long m3 = __ballot(a3 > 0.5f);
            int rf[4], rb[4];
            mask_dists(m0, m1, m2, m3, lane, rf);
            mask_dists(~m0, ~m1, ~m2, ~m3, lane, rb);
            #pragma unroll
            for (int k = 0; k < 4; ++k)
                rows[s][(k << 6) + lane] = (unsigned)rf[k] | ((unsigned)rb[k] << 16);
        }
    }

    // hot loads for the loss phase (issue early, overlap with barrier + window min)
    const float x0 = pimg[py0 * W + px];
    const float x1 = pimg[py1 * W + px];
    const float t0 = timg[py0 * W + px];
    const float t1 = timg[py1 * W + px];

    __syncthreads();

    // ---- windowed column pass for both output rows from LDS ----
    int bf0 = INT_MAX, bb0 = INT_MAX, bf1 = INT_MAX, bb1 = INT_MAX;
    #pragma unroll
    for (int s = 0; s < 8; ++s) {
        const int qy = py0 - 3 + s;
        if (qy >= 0 && qy < H) {            // wave-uniform
            const unsigned v = rows[s][px];
            const int rfv = (int)(v & 0xffffu);
            const int rbv = (int)(v >> 16);
            const int rf2 = rfv * rfv, rb2 = rbv * rbv;
            const int d0 = s - 3, d1v = s - 4;
            bf0 = min(bf0, rf2 + d0 * d0);  bb0 = min(bb0, rb2 + d0 * d0);
            bf1 = min(bf1, rf2 + d1v * d1v); bb1 = min(bb1, rb2 + d1v * d1v);
        }
    }

    // ---- rare exact fallback: extend outward, recomputing rows on demand ----
    // Each wave loads the full row, ballots (identical masks), and every thread
    // computes its own pixel's distance: word index = wid (wave-uniform), bit = lane.
    for (int dir = 0; dir < 2; ++dir) {
        const int qy_start = dir ? py0 + 5 : py0 - 4;
        const int qy_step  = dir ? 1 : -1;
        for (int qy = qy_start; qy >= 0 && qy < H; qy += qy_step) {
            const int dd = dir ? (qy - py0) : (py0 - qy);
            const int du1 = dir ? (dd - 1) : (dd + 1);
            const int d0s = dd * dd, d1s = du1 * du1;
            if (!__any((d0s < bf0) | (d0s < bb0) | (d1s < bf1) | (d1s < bb1))) break;
            const float a0 = timg[qy * W + lane];
            const float a1 = timg[qy * W + 64 + lane];
            const float a2 = timg[qy * W + 128 + lane];
            const float a3 = timg[qy * W + 192 + lane];
            const unsigned long long m0 = __ballot(a0 > 0.5f);
            const unsigned long long m1 = __ballot(a1 > 0.5f);
            const unsigned long long m2 = __ballot(a2 > 0.5f);
            const unsigned long long m3 = __ballot(a3 > 0.5f);
            // chains for fg and bg
            int rfv, rbv;
            {
                const int f1 = __ffsll((long long)m1), f2 = __ffsll((long long)m2), f3 = __ffsll((long long)m3);
                const int d3 = f3 ? f3 - 1 : BIGD;
                const int d2 = f2 ? f2 - 1 : 64 + d3;
                const int d1c = f1 ? f1 - 1 : 64 + d2;
                const int c0 = __clzll((long long)m0), c1 = __clzll((long long)m1), c2 = __clzll((long long)m2);
                const int e0 = (c0 < 64) ? c0 : BIGD;
                const int e1 = (c1 < 64) ? c1 : 64 + e0;
                const int e2 = (c2 < 64) ? c2 : 64 + e1;
                const unsigned long long mw = (wid == 0) ? m0 : (wid == 1) ? m1 : (wid == 2) ? m2 : m3;
                const int dnx = (wid == 0) ? d1c : (wid == 1) ? d2 : (wid == 2) ? d3 : BIGD;
                const int epv = (wid == 0) ? BIGD : (wid == 1) ? e0 : (wid == 2) ? e1 : e2;
                const unsigned long long x = mw >> lane;
                const int fx = __ffsll((long long)x);
                const int dR = fx ? fx - 1 : (64 - lane) + dnx;
                const unsigned long long y = mw << (63 - lane);
                const int cy = __clzll((long long)y);
                const int dL = (cy < 64) ? cy : (lane + 1) + epv;
                int rr = min(dL, dR); if (rr > 255) rr = RSENT;
                rfv = rr;
            }
            {
                const unsigned long long b0 = ~m0, b1 = ~m1, b2 = ~m2, b3 = ~m3;
                const int f1 = __ffsll((long long)b1), f2 = __ffsll((long long)b2), f3 = __ffsll((long long)b3);
                const int d3 = f3 ? f3 - 1 : BIGD;
                const int d2 = f2 ? f2 - 1 : 64 + d3;
                const int d1c = f1 ? f1 - 1 : 64 + d2;
                const int c0 = __clzll((long long)b0), c1 = __clzll((long long)b1), c2 = __clzll((long long)b2);
                const int e0 = (c0 < 64) ? c0 : BIGD;
                const int e1 = (c1 < 64) ? c1 : 64 + e0;
                const int e2 = (c2 < 64) ? c2 : 64 + e1;
                const unsigned long long mw = (wid == 0) ? b0 : (wid == 1) ? b1 : (wid == 2) ? b2 : b3;
                const int dnx = (wid == 0) ? d1c : (wid == 1) ? d2 : (wid == 2) ? d3 : BIGD;
                const int epv = (wid == 0) ? BIGD : (wid == 1) ? e0 : (wid == 2) ? e1 : e2;
                const unsigned long long x = mw >> lane;
                const int fx = __ffsll((long long)x);
                const int dR = fx ? fx - 1 : (64 - lane) + dnx;
                const unsigned long long y = mw << (63 - lane);
                const int cy = __clzll((long long)y);
                const int dL = (cy < 64) ? cy : (lane + 1) + epv;
                int rr = min(dL, dR); if (rr > 255) rr = RSENT;
                rbv = rr;
            }
            const int rf2 = rfv * rfv, rb2 = rbv * rbv;
            bf0 = min(bf0, rf2 + d0s); bb0 = min(bb0, rb2 + d0s);
            bf1 = min(bf1, rf2 + d1s); bb1 = min(bb1, rb2 + d1s);
        }
    }

    // ---- loss math (identical ops/order to the verified kernel) ----
    const float MAXD2 = (float)((H - 1) * (H - 1) + (W - 1) * (W - 1));
    const float Df0 = (bf0 > EMPTY_THRESH) ? MAXD2 : (float)bf0;
    const float Db0 = (bb0 > EMPTY_THRESH) ? MAXD2 : (float)bb0;
    const float Df1 = (bf1 > EMPTY_THRESH) ? MAXD2 : (float)bf1;
    const float Db1 = (bb1 > EMPTY_THRESH) ? MAXD2 : (float)bb1;

    const float p0   = 1.0f / (1.0f + expf(-x0));
    const float phi0 = (t0 > 0.5f) ? -sqrtf(Db0) : sqrtf(Df0);
    const float pc0  = fminf(fmaxf(p0, FEPS), 1.0f - FEPS);
    const float pt0  = pc0 * t0 + (1.0f - pc0) * (1.0f - t0);
    const float at0  = 0.25f * t0 + 0.75f * (1.0f - t0);
    const float om0  = 1.0f - pt0;
    const float fo0  = -at0 * om0 * om0 * logf(pt0);

    const float p1   = 1.0f / (1.0f + expf(-x1));
    const float phi1 = (t1 > 0.5f) ? -sqrtf(Db1) : sqrtf(Df1);
    const float pc1  = fminf(fmaxf(p1, FEPS), 1.0f - FEPS);
    const float pt1  = pc1 * t1 + (1.0f - pc1) * (1.0f - t1);
    const float at1  = 0.25f * t1 + 0.75f * (1.0f - t1);
    const float om1  = 1.0f - pt1;
    const float fo1  = -at1 * om1 * om1 * logf(pt1);

    // ---- per-row block reductions (same tree as before -> bitwise-identical parts) ----
    float v50[5] = { p0 * t0, p0, t0, phi0 * p0, fo0 };
    float v51[5] = { p1 * t1, p1, t1, phi1 * p1, fo1 };
    #pragma unroll
    for (int q = 0; q < 5; ++q) {
        float a = v50[q], b = v51[q];
        #pragma unroll
        for (int off = 32; off > 0; off >>= 1) {
            a += __shfl_down(a, off, 64);
            b += __shfl_down(b, off, 64);
        }
        v50[q] = a; v51[q] = b;
    }
    if (lane == 0) {
        #pragma unroll
        for (int q = 0; q < 5; ++q) {
            smem[0][wid * 5 + q] = v50[q];
            smem[1][wid * 5 + q] = v51[q];
        }
    }
    __syncthreads();
    if (px == 0) {
        // publish parts with RELAXED agent-scope stores (no L2 writeback/invalidate),
        // then order the flag store behind them with a bare vmcnt wait.
        #pragma unroll
        for (int r = 0; r < 2; ++r) {
            #pragma unroll
            for (int q = 0; q < 5; ++q) {
                const float v = smem[r][q] + smem[r][5 + q] + smem[r][10 + q] + smem[r][15 + q];
                __hip_atomic_store(&parts[q * NROW + blk * 2 + r], v,
                                   __ATOMIC_RELAXED, __HIP_MEMORY_SCOPE_AGENT);
            }
        }
        asm volatile("s_waitcnt vmcnt(0)" ::: "memory");
        __hip_atomic_store(&flags[blk], MAGIC, __ATOMIC_RELAXED, __HIP_MEMORY_SCOPE_AGENT);
    }

    // ---- block 0: wait for all producers, then finalize (identical reduction) ----
    if (blk == 0) {
        const int tid = px;
        bool done = false;
        int guard = 0;
        do {
            bool mine = true;
            #pragma unroll
            for (int k = 0; k < NBLK / 256; ++k) {
                const unsigned long long v = __hip_atomic_load(
                    &flags[tid + k * 256], __ATOMIC_RELAXED, __HIP_MEMORY_SCOPE_AGENT);
                mine = mine && (v == MAGIC);
            }
            done = (__syncthreads_and((int)mine) != 0);
            if (!done) __builtin_amdgcn_s_sleep(2);
        } while (!done && (++guard < (1 << 26)));

        // boundary + focal: global sums over all NROW partials
        float bp = 0.0f, fc = 0.0f;
        for (int k = tid; k < NROW; k += 256) {
            bp += __hip_atomic_load(&parts[3 * NROW + k], __ATOMIC_RELAXED, __HIP_MEMORY_SCOPE_AGENT);
            fc += __hip_atomic_load(&parts[4 * NROW + k], __ATOMIC_RELAXED, __HIP_MEMORY_SCOPE_AGENT);
        }
        #pragma unroll
        for (int off = 32; off > 0; off >>= 1) {
            bp += __shfl_down(bp, off, 64);
            fc += __shfl_down(fc, off, 64);
        }
        if (lane == 0) { smf[wid * 2] = bp; smf[wid * 2 + 1] = fc; }

        // dice: each wave handles 2 images (256 partials each)
        #pragma unroll
        for (int mi = 0; mi < 2; ++mi) {
            const int m = wid * 2 + mi;
            float A = 0.f, S = 0.f, C = 0.f;
            #pragma unroll
            for (int k = 0; k < 4; ++k) {
                const int i = m * 256 + k * 64 + lane;
                A += __hip_atomic_load(&parts[0 * NROW + i], __ATOMIC_RELAXED, __HIP_MEMORY_SCOPE_AGENT);
                S += __hip_atomic_load(&parts[1 * NROW + i], __ATOMIC_RELAXED, __HIP_MEMORY_SCOPE_AGENT);
                C += __hip_atomic_load(&parts[2 * NROW + i], __ATOMIC_RELAXED, __HIP_MEMORY_SCOPE_AGENT);
            }
            #pragma unroll
            for (int off = 32; off > 0; off >>= 1) {
                A += __shfl_down(A, off, 64);
                S += __shfl_down(S, off, 64);
                C += __shfl_down(C, off, 64);
            }
            if (lane == 0) sratio[m] = (2.0f * A + FEPS) / (S + C + FEPS);
        }
        __syncthreads();
        if (tid == 0) {
            const float B = smf[0] + smf[2] + smf[4] + smf[6];
            const float F = smf[1] + smf[3] + smf[5] + smf[7];
            float dacc = 0.0f;
            #pragma unroll
            for (int m = 0; m < 8; ++m) dacc += sratio[m];
            const float dice_val     = 1.0f - dacc / (float)N;
            const float boundary_val = B / (float)NPIX;
            const float focal_val    = F / (float)NPIX;
            out[0] = dice_val + boundary_val + focal_val;   // loss
            out[1] = dice_val;
            out[2] = boundary_val;
            out[3] = focal_val;
        }
    }
}

extern "C" void kernel_launch(void* const* d_in, const int* in_sizes, int n_in,
                              void* d_out, int out_size, void* d_ws, size_t ws_size,
                              hipStream_t stream)
{
    const float* pred = (const float*)d_in[0];
    const float* tgt  = (const float*)d_in[1];
    float* out = (float*)d_out;

    float* parts = (float*)d_ws;                                        // 40 KB
    unsigned long long* flags =
        (unsigned long long*)((char*)d_ws + (size_t)5 * NROW * sizeof(float)); // 8 KB

    fused_kernel<<<NBLK, 256, 0, stream>>>(pred, tgt, parts, flags, out);
}